// Round 7
// baseline (3370.398 us; speedup 1.0000x reference)
//
#include <hip/hip_runtime.h>

typedef __attribute__((ext_vector_type(8))) short short8;
typedef __attribute__((ext_vector_type(4))) float f32x4;
typedef unsigned long long u64;

constexpr int NN = 100000;
constexpr int EE = 1600000;
constexpr int NF = 512;
constexpr int NH = 256;
constexpr int NC = 32;
constexpr int KP = 10;
constexpr int PBLK = 768;     // prop blocks (3/CU on 256 CUs -> co-resident)
constexpr int NPB = 131;      // nodes per prop block: 768*131 = 100608 >= NN

__device__ __forceinline__ unsigned short f2bf(float f) {
  unsigned int u = __float_as_uint(f);
  u += 0x7FFFu + ((u >> 16) & 1u);   // round-to-nearest-even
  return (unsigned short)(u >> 16);
}
__device__ __forceinline__ float bf2f(unsigned short s) {
  return __uint_as_float(((unsigned int)s) << 16);
}

__device__ __forceinline__ short8 cvt8(float4 a0, float4 a1) {
  union { unsigned int u[4]; short8 s; } r;
  asm("v_cvt_pk_bf16_f32 %0, %1, %2" : "=v"(r.u[0]) : "v"(a0.x), "v"(a0.y));
  asm("v_cvt_pk_bf16_f32 %0, %1, %2" : "=v"(r.u[1]) : "v"(a0.z), "v"(a0.w));
  asm("v_cvt_pk_bf16_f32 %0, %1, %2" : "=v"(r.u[2]) : "v"(a1.x), "v"(a1.y));
  asm("v_cvt_pk_bf16_f32 %0, %1, %2" : "=v"(r.u[3]) : "v"(a1.z), "v"(a1.w));
  return r.s;
}

// Barrier with LDS-only drain: keeps global loads (into registers) in flight
// across the barrier — avoids the compiler's vmcnt(0) drain of __syncthreads.
__device__ __forceinline__ void block_sync_lds() {
  asm volatile("s_waitcnt lgkmcnt(0)" ::: "memory");
  __builtin_amdgcn_s_barrier();
}

// ---- weight conversion: Wt[col][k]=bf(Ws[k][col]); Web[col][k]=bf(We[k][col])
__global__ void convwb_kernel(const float* __restrict__ Ws, const float* __restrict__ We,
                              unsigned short* __restrict__ Wt, unsigned short* __restrict__ Web) {
  int idx = blockIdx.x * 256 + threadIdx.x;      // 544*256 = 139264
  if (idx < 131072) {
    int col = idx >> 9, k = idx & 511;
    Wt[idx] = f2bf(Ws[(size_t)k * NH + col]);
  } else {
    int j = idx - 131072;
    int col = j >> 8, k = j & 255;
    Web[j] = f2bf(We[(size_t)k * NC + col]);
  }
}

// ---- GEMM1: H = relu(X[100000,512] @ W[512,256] + b), bf16 MFMA ------------
// R3 structure (best measured: 134 us). 256 thr = 4 waves (2x2), wave tile
// 64x64, block tile 128x128, BK=32, PAD=36, depth-3 reg ring, lgkm-only
// barriers. Do not touch: R1/R2/R4 redesigns all regressed.
__global__ __launch_bounds__(256, 3) void gemm1_kernel(
    const float* __restrict__ X, const unsigned short* __restrict__ Wt,
    const float* __restrict__ bias, unsigned short* __restrict__ H) {
  constexpr int PAD = 36;
  __shared__ __align__(16) unsigned short Asm[2][128 * PAD];
  __shared__ __align__(16) unsigned short Bsm[2][128 * PAD];
  const int tid = threadIdx.x;
  const int lane = tid & 63;
  const int wave = tid >> 6;
  const int wm = wave >> 1, wn = wave & 1;
  const int l15 = lane & 15, kq = lane >> 4;
  const int m0 = (blockIdx.x >> 1) * 128;
  const int n0 = (blockIdx.x & 1) * 128;

  const int arl0 = tid >> 2, aq = tid & 3;
  int ar0 = m0 + arl0; if (ar0 >= NN) ar0 = NN - 1;
  int ar1 = m0 + arl0 + 64; if (ar1 >= NN) ar1 = NN - 1;
  const float* aptr0 = X + (size_t)ar0 * NF + aq * 8;
  const float* aptr1 = X + (size_t)ar1 * NF + aq * 8;
  const int awr0 = arl0 * PAD + aq * 8;
  const int awr1 = awr0 + 64 * PAD;
  const int bcl = tid >> 1, bh = tid & 1;
  const unsigned short* bptr = Wt + (size_t)(n0 + bcl) * NF + bh * 16;
  const int bwr = bcl * PAD + bh * 16;

  f32x4 acc[4][4];
#pragma unroll
  for (int m = 0; m < 4; m++)
#pragma unroll
    for (int n = 0; n < 4; n++) acc[m][n] = (f32x4)0.0f;

  float4 ra[3][4]; short8 rb0[3], rb1[3];   // depth-3 prefetch ring

#define LOADR(ks, j) do { \
    ra[j][0] = *reinterpret_cast<const float4*>(aptr0 + (ks) * 32); \
    ra[j][1] = *reinterpret_cast<const float4*>(aptr0 + (ks) * 32 + 4); \
    ra[j][2] = *reinterpret_cast<const float4*>(aptr1 + (ks) * 32); \
    ra[j][3] = *reinterpret_cast<const float4*>(aptr1 + (ks) * 32 + 4); \
    rb0[j] = *reinterpret_cast<const short8*>(bptr + (ks) * 32); \
    rb1[j] = *reinterpret_cast<const short8*>(bptr + (ks) * 32 + 8); \
  } while (0)

#define STAGE(b, j) do { \
    *reinterpret_cast<short8*>(&Asm[b][awr0]) = cvt8(ra[j][0], ra[j][1]); \
    *reinterpret_cast<short8*>(&Asm[b][awr1]) = cvt8(ra[j][2], ra[j][3]); \
    *reinterpret_cast<short8*>(&Bsm[b][bwr]) = rb0[j]; \
    *reinterpret_cast<short8*>(&Bsm[b][bwr + 8]) = rb1[j]; \
  } while (0)

#define COMPUTE(b) do { \
    short8 af[4], bfr[4]; \
    _Pragma("unroll") \
    for (int mi = 0; mi < 4; mi++) \
      af[mi] = *reinterpret_cast<const short8*>(&Asm[b][(wm * 64 + mi * 16 + l15) * PAD + kq * 8]); \
    _Pragma("unroll") \
    for (int ni = 0; ni < 4; ni++) \
      bfr[ni] = *reinterpret_cast<const short8*>(&Bsm[b][(wn * 64 + ni * 16 + l15) * PAD + kq * 8]); \
    _Pragma("unroll") \
    for (int mi = 0; mi < 4; mi++) \
      _Pragma("unroll") \
      for (int ni = 0; ni < 4; ni++) \
        acc[mi][ni] = __builtin_amdgcn_mfma_f32_16x16x32_bf16(af[mi], bfr[ni], acc[mi][ni], 0, 0, 0); \
  } while (0)

  LOADR(0, 0);
  LOADR(1, 1);
  LOADR(2, 2);
  STAGE(0, 0);
  block_sync_lds();

#pragma unroll
  for (int p = 0; p < 16; p++) {
    if (p + 3 < 16) LOADR(p + 3, (p + 3) % 3);
    COMPUTE(p & 1);
    if (p + 1 < 16) STAGE((p + 1) & 1, (p + 1) % 3);
    block_sync_lds();
  }
#undef LOADR
#undef STAGE
#undef COMPUTE

  // epilogue: bias + relu, store bf16.  C/D layout: col=lane&15, row=(lane>>4)*4+i
#pragma unroll
  for (int ni = 0; ni < 4; ni++) {
    int col = n0 + wn * 64 + ni * 16 + l15;
    float bsv = bias[col];
#pragma unroll
    for (int mi = 0; mi < 4; mi++) {
      int rb2 = m0 + wm * 64 + mi * 16 + kq * 4;
#pragma unroll
      for (int i = 0; i < 4; i++) {
        int r = rb2 + i;
        if (r < NN) {
          float v = acc[mi][ni][i] + bsv;
          H[(size_t)r * NH + col] = f2bf(v > 0.f ? v : 0.f);
        }
      }
    }
  }
}

// ---- GEMM2 (MFMA): h2 = relu(H @ We + be); x0b = bf16(h2); out = t0*h2 -----
__global__ __launch_bounds__(256) void gemm2_kernel(
    const unsigned short* __restrict__ H, const unsigned short* __restrict__ Web,
    const float* __restrict__ be, const float* __restrict__ temp,
    unsigned short* __restrict__ x0b, float* __restrict__ out) {
  const int tid = threadIdx.x;
  const int lane = tid & 63;
  const int wave = tid >> 6;
  const int l15 = lane & 15, kq = lane >> 4;
  const int rbase = blockIdx.x * 64 + wave * 16;
  int rr = rbase + l15; if (rr >= NN) rr = NN - 1;
  const unsigned short* hrow = H + (size_t)rr * NH + kq * 8;
  const unsigned short* wrow = Web + (size_t)l15 * 256 + kq * 8;

  f32x4 acc[2];
  acc[0] = (f32x4)0.0f; acc[1] = (f32x4)0.0f;
#pragma unroll
  for (int ks = 0; ks < 8; ks++) {
    short8 a = *reinterpret_cast<const short8*>(hrow + ks * 32);
    short8 b0 = *reinterpret_cast<const short8*>(wrow + ks * 32);
    short8 b1 = *reinterpret_cast<const short8*>(wrow + 16 * 256 + ks * 32);
    acc[0] = __builtin_amdgcn_mfma_f32_16x16x32_bf16(a, b0, acc[0], 0, 0, 0);
    acc[1] = __builtin_amdgcn_mfma_f32_16x16x32_bf16(a, b1, acc[1], 0, 0, 0);
  }
  const float t0 = temp[0];
#pragma unroll
  for (int nt = 0; nt < 2; nt++) {
    int col = nt * 16 + l15;
    float bv = be[col];
#pragma unroll
    for (int i = 0; i < 4; i++) {
      int row = rbase + kq * 4 + i;
      if (row < NN) {
        float v = acc[nt][i] + bv;
        v = v > 0.f ? v : 0.f;
        x0b[(size_t)row * NC + col] = f2bf(v);
        out[(size_t)row * NC + col] = t0 * v;
      }
    }
  }
}

// ---- graph normalization + CSR build ---------------------------------------
// dc[i]: bits[63:44] = count, bits[43:0] = fixed-point deg (scale 2^32)
// Also zeroes the prop grid-barrier counter each replay (runs before prop).
__global__ void node_init_kernel(u64* dc, int* bar) {
  int i = blockIdx.x * 256 + threadIdx.x;
  if (i == 0) *bar = 0;
  if (i < NN) dc[i] = (1ULL << 44) | (1ULL << 32);   // self-loop: cnt=1, deg=1.0
}

__global__ void edge_deg_kernel(const int* __restrict__ ei, const float* __restrict__ ew,
                                u64* dc) {
  int e = blockIdx.x * 256 + threadIdx.x;
  if (e < EE) {
    int col = ei[EE + e];
    u64 v = (1ULL << 44) | (u64)((double)ew[e] * 4294967296.0);
    atomicAdd(&dc[col], v);
  }
}

__global__ void dis_kernel(const u64* __restrict__ dc, float* __restrict__ dis,
                           int* __restrict__ cnt) {
  int i = blockIdx.x * 256 + threadIdx.x;
  if (i < NN) {
    u64 v = dc[i];
    cnt[i] = (int)(v >> 44);
    float deg = (float)((double)(v & 0xFFFFFFFFFFFULL) * (1.0 / 4294967296.0));
    dis[i] = rsqrtf(deg);
  }
}

__global__ void scan1_kernel(const int* __restrict__ cnt, int* bsum) {
  __shared__ int ws[4];
  const int tid = threadIdx.x;
  int base = blockIdx.x * 1024 + tid * 4;
  int s = 0;
#pragma unroll
  for (int j = 0; j < 4; j++) { int i = base + j; if (i < NN) s += cnt[i]; }
  for (int off = 32; off > 0; off >>= 1) s += __shfl_down(s, off);
  if ((tid & 63) == 0) ws[tid >> 6] = s;
  __syncthreads();
  if (tid == 0) bsum[blockIdx.x] = ws[0] + ws[1] + ws[2] + ws[3];
}

__global__ void scan2_kernel(const int* __restrict__ bsum, int* bofs, int* offs) {
  if (threadIdx.x == 0) {
    int run = 0;
    for (int i = 0; i < 98; i++) { bofs[i] = run; run += bsum[i]; }
    offs[NN] = run;
  }
}

__global__ void scan3_kernel(const int* __restrict__ cnt, const int* __restrict__ bofs,
                             int* offs, int* cursor) {
  __shared__ int wsum[4];
  const int tid = threadIdx.x;
  const int lane = tid & 63, wv = tid >> 6;
  int base = blockIdx.x * 1024 + tid * 4;
  int v[4]; int s = 0;
#pragma unroll
  for (int j = 0; j < 4; j++) { int i = base + j; v[j] = (i < NN) ? cnt[i] : 0; s += v[j]; }
  int incl = s;
  for (int off = 1; off < 64; off <<= 1) {
    int t = __shfl_up(incl, off);
    if (lane >= off) incl += t;
  }
  if (lane == 63) wsum[wv] = incl;
  __syncthreads();
  int woff = bofs[blockIdx.x];
  for (int w = 0; w < wv; w++) woff += wsum[w];
  int excl = woff + incl - s;
#pragma unroll
  for (int j = 0; j < 4; j++) {
    int i = base + j;
    if (i < NN) { offs[i] = excl; cursor[i] = excl; }
    excl += v[j];
  }
}

// pk[slot]: low 32 = row index, high 32 = fp32 weight bits
__global__ void fill_kernel(const int* __restrict__ ei, const float* __restrict__ ew,
                            const float* __restrict__ dis, int* cursor,
                            u64* __restrict__ pk) {
  int t = blockIdx.x * 256 + threadIdx.x;
  if (t < EE) {
    int r = ei[t], c = ei[EE + t];
    int slot = atomicAdd(&cursor[c], 1);
    unsigned int wb = __float_as_uint(dis[r] * ew[t] * dis[c]);
    pk[slot] = (u64)(unsigned int)r | ((u64)wb << 32);
  } else if (t < EE + NN) {
    int i = t - EE;
    int slot = atomicAdd(&cursor[i], 1);
    float d = dis[i];
    unsigned int wb = __float_as_uint(d * d);
    pk[slot] = (u64)(unsigned int)i | ((u64)wb << 32);
  }
}

// ---- fused K=10 propagation: persistent + software grid barrier ------------
// 768 blocks x 256 thr, __launch_bounds__(256,3) -> 3 blocks/CU co-resident by
// construction (grid == 256 CU x 3), so the spin barrier cannot deadlock.
// Barrier: release fence + atomicAdd, spin on agent-scope acquire load, then
// acquire fence by ALL threads (invalidates stale L1/XCD-L2 lines).
// Block owns 131 nodes; out accumulated in registers, written once at end.
__device__ __forceinline__ void grid_bar(int* bar, int target) {
  __syncthreads();
  if (threadIdx.x == 0) {
    __threadfence();                        // release: publish xout writes
    atomicAdd(bar, 1);
    while (__hip_atomic_load(bar, __ATOMIC_ACQUIRE, __HIP_MEMORY_SCOPE_AGENT) < target) {
      __builtin_amdgcn_s_sleep(8);
    }
  }
  __syncthreads();
  __threadfence();                          // acquire: invalidate stale caches
}

__global__ __launch_bounds__(256, 3) void prop_kernel(
    const int* __restrict__ offs, const u64* __restrict__ pk,
    unsigned short* __restrict__ bufA, unsigned short* __restrict__ bufB,
    float* __restrict__ out, const float* __restrict__ temp, int* bar) {
  const int tid = threadIdx.x;
  const int slot = tid >> 5;
  const int f = tid & 31;
  const int base = blockIdx.x * NPB;

  float racc[17];
#pragma unroll
  for (int r = 0; r < 17; r++) racc[r] = 0.f;

  const unsigned short* xin = bufA;
  unsigned short* xout = bufB;
  int target = 0;
  for (int k = 0; k < KP; k++) {
    const float tkv = temp[k + 1];
#pragma unroll
    for (int r = 0; r < 17; r++) {
      const int li = r * 8 + slot;
      const int node = base + li;
      if (li < NPB && node < NN) {
        const int s = offs[node], e = offs[node + 1];   // L1-hot after iter 0
        float aa[4] = {0.f, 0.f, 0.f, 0.f};
        int j = s;
        for (; j + 16 <= e; j += 16) {
          u64 p[16];
#pragma unroll
          for (int i = 0; i < 16; i++) p[i] = pk[j + i];
          float x[16];
#pragma unroll
          for (int i = 0; i < 16; i++)
            x[i] = bf2f(xin[(size_t)(unsigned int)p[i] * NC + f]);
#pragma unroll
          for (int i = 0; i < 16; i++)
            aa[i & 3] += __uint_as_float((unsigned int)(p[i] >> 32)) * x[i];
        }
        if (j + 4 <= e) {
          u64 p[4];
#pragma unroll
          for (int i = 0; i < 4; i++) p[i] = pk[j + i];
          float x[4];
#pragma unroll
          for (int i = 0; i < 4; i++)
            x[i] = bf2f(xin[(size_t)(unsigned int)p[i] * NC + f]);
#pragma unroll
          for (int i = 0; i < 4; i++)
            aa[i] += __uint_as_float((unsigned int)(p[i] >> 32)) * x[i];
          j += 4;
          if (j + 4 <= e) {
            u64 q[4];
#pragma unroll
            for (int i = 0; i < 4; i++) q[i] = pk[j + i];
            float y[4];
#pragma unroll
            for (int i = 0; i < 4; i++)
              y[i] = bf2f(xin[(size_t)(unsigned int)q[i] * NC + f]);
#pragma unroll
            for (int i = 0; i < 4; i++)
              aa[i] += __uint_as_float((unsigned int)(q[i] >> 32)) * y[i];
            j += 4;
          }
        }
        for (; j < e; j++) {
          u64 p0 = pk[j];
          aa[0] += __uint_as_float((unsigned int)(p0 >> 32)) * bf2f(xin[(size_t)(unsigned int)p0 * NC + f]);
        }
        const float acc = (aa[0] + aa[1]) + (aa[2] + aa[3]);
        racc[r] += tkv * acc;
        if (k < KP - 1) xout[(size_t)node * NC + f] = f2bf(acc);
      }
    }
    if (k < KP - 1) {
      target += PBLK;
      grid_bar(bar, target);
      unsigned short* t = xout; xout = (unsigned short*)xin; xin = t;
    }
  }

  // epilogue: single out RMW (gemm2 wrote the temp[0]*h term)
#pragma unroll
  for (int r = 0; r < 17; r++) {
    const int li = r * 8 + slot;
    const int node = base + li;
    if (li < NPB && node < NN) out[(size_t)node * NC + f] += racc[r];
  }
}

extern "C" void kernel_launch(void* const* d_in, const int* in_sizes, int n_in,
                              void* d_out, int out_size, void* d_ws, size_t ws_size,
                              hipStream_t stream) {
  const float* X    = (const float*)d_in[0];
  const float* EA   = (const float*)d_in[1];
  const float* Ws   = (const float*)d_in[2];
  const float* bs   = (const float*)d_in[3];
  const float* We   = (const float*)d_in[4];
  const float* be   = (const float*)d_in[5];
  const float* temp = (const float*)d_in[6];
  const int*   ei   = (const int*)d_in[7];
  float* out = (float*)d_out;

  size_t off = 0;
  auto alloc = [&](size_t n) { void* p = (char*)d_ws + off; off += (n + 255) & ~(size_t)255; return p; };
  unsigned short* Wt  = (unsigned short*)alloc((size_t)NF * NH * 2);   // 256 KB
  unsigned short* Web = (unsigned short*)alloc((size_t)NH * NC * 2);   // 16 KB
  unsigned short* H   = (unsigned short*)alloc((size_t)NN * NH * 2);   // 51.2 MB
  unsigned short* xk0 = (unsigned short*)alloc((size_t)NN * NC * 2);   // 6.4 MB
  unsigned short* xk1 = (unsigned short*)alloc((size_t)NN * NC * 2);   // 6.4 MB
  u64*   dc   = (u64*)alloc((size_t)NN * 8);                           // 800 KB
  float* dis  = (float*)alloc((size_t)NN * 4);
  int*   cnt  = (int*)alloc((size_t)NN * 4);
  int*   offs = (int*)alloc((size_t)(NN + 1) * 4);
  int*   cursor = (int*)alloc((size_t)NN * 4);
  int*   bsum = (int*)alloc(98 * 4);
  int*   bofs = (int*)alloc(98 * 4);
  u64*   pk   = (u64*)alloc((size_t)(EE + NN) * 8);                    // 13.6 MB
  int*   bar  = (int*)alloc(256);                                      // grid barrier

  // MLP front-end
  convwb_kernel<<<544, 256, 0, stream>>>(Ws, We, Wt, Web);
  gemm1_kernel<<<1564, 256, 0, stream>>>(X, Wt, bs, H);
  gemm2_kernel<<<1563, 256, 0, stream>>>(H, Web, be, temp, xk0, out);

  // gcn_norm + CSR build (by col, so SpMM is atomic-free)
  node_init_kernel<<<391, 256, 0, stream>>>(dc, bar);
  edge_deg_kernel<<<6250, 256, 0, stream>>>(ei, EA, dc);
  dis_kernel<<<391, 256, 0, stream>>>(dc, dis, cnt);
  scan1_kernel<<<98, 256, 0, stream>>>(cnt, bsum);
  scan2_kernel<<<1, 64, 0, stream>>>(bsum, bofs, offs);
  scan3_kernel<<<98, 256, 0, stream>>>(cnt, bofs, offs, cursor);
  fill_kernel<<<6641, 256, 0, stream>>>(ei, EA, dis, cursor, pk);

  // K=10 propagation, fused: persistent kernel + software grid barrier
  prop_kernel<<<PBLK, 256, 0, stream>>>(offs, pk, xk0, xk1, out, temp, bar);
}

// Round 8
// 689.373 us; speedup vs baseline: 4.8891x; 4.8891x over previous
//
#include <hip/hip_runtime.h>

typedef __attribute__((ext_vector_type(8))) short short8;
typedef __attribute__((ext_vector_type(4))) float f32x4;
typedef unsigned long long u64;

constexpr int NN = 100000;
constexpr int EE = 1600000;
constexpr int NF = 512;
constexpr int NH = 256;
constexpr int NC = 32;
constexpr int KP = 10;

__device__ __forceinline__ unsigned short f2bf(float f) {
  unsigned int u = __float_as_uint(f);
  u += 0x7FFFu + ((u >> 16) & 1u);   // round-to-nearest-even
  return (unsigned short)(u >> 16);
}
__device__ __forceinline__ float bf2f(unsigned short s) {
  return __uint_as_float(((unsigned int)s) << 16);
}
__device__ __forceinline__ int padc(int c) { return (c + 15) & ~15; }

__device__ __forceinline__ short8 cvt8(float4 a0, float4 a1) {
  union { unsigned int u[4]; short8 s; } r;
  asm("v_cvt_pk_bf16_f32 %0, %1, %2" : "=v"(r.u[0]) : "v"(a0.x), "v"(a0.y));
  asm("v_cvt_pk_bf16_f32 %0, %1, %2" : "=v"(r.u[1]) : "v"(a0.z), "v"(a0.w));
  asm("v_cvt_pk_bf16_f32 %0, %1, %2" : "=v"(r.u[2]) : "v"(a1.x), "v"(a1.y));
  asm("v_cvt_pk_bf16_f32 %0, %1, %2" : "=v"(r.u[3]) : "v"(a1.z), "v"(a1.w));
  return r.s;
}

// Barrier with LDS-only drain: keeps global loads (into registers) in flight
// across the barrier — avoids the compiler's vmcnt(0) drain of __syncthreads.
__device__ __forceinline__ void block_sync_lds() {
  asm volatile("s_waitcnt lgkmcnt(0)" ::: "memory");
  __builtin_amdgcn_s_barrier();
}

// ---- weight conversion: Wt[col][k]=bf(Ws[k][col]); Web[col][k]=bf(We[k][col])
__global__ void convwb_kernel(const float* __restrict__ Ws, const float* __restrict__ We,
                              unsigned short* __restrict__ Wt, unsigned short* __restrict__ Web) {
  int idx = blockIdx.x * 256 + threadIdx.x;      // 544*256 = 139264
  if (idx < 131072) {
    int col = idx >> 9, k = idx & 511;
    Wt[idx] = f2bf(Ws[(size_t)k * NH + col]);
  } else {
    int j = idx - 131072;
    int col = j >> 8, k = j & 255;
    Web[j] = f2bf(We[(size_t)k * NC + col]);
  }
}

// ---- GEMM1: H = relu(X[100000,512] @ W[512,256] + b), bf16 MFMA ------------
// R3 structure (best measured: 134 us). Do not touch: R1/R2/R4 redesigns all
// regressed; R7 confirmed this is the stable local optimum.
__global__ __launch_bounds__(256, 3) void gemm1_kernel(
    const float* __restrict__ X, const unsigned short* __restrict__ Wt,
    const float* __restrict__ bias, unsigned short* __restrict__ H) {
  constexpr int PAD = 36;
  __shared__ __align__(16) unsigned short Asm[2][128 * PAD];
  __shared__ __align__(16) unsigned short Bsm[2][128 * PAD];
  const int tid = threadIdx.x;
  const int lane = tid & 63;
  const int wave = tid >> 6;
  const int wm = wave >> 1, wn = wave & 1;
  const int l15 = lane & 15, kq = lane >> 4;
  const int m0 = (blockIdx.x >> 1) * 128;
  const int n0 = (blockIdx.x & 1) * 128;

  const int arl0 = tid >> 2, aq = tid & 3;
  int ar0 = m0 + arl0; if (ar0 >= NN) ar0 = NN - 1;
  int ar1 = m0 + arl0 + 64; if (ar1 >= NN) ar1 = NN - 1;
  const float* aptr0 = X + (size_t)ar0 * NF + aq * 8;
  const float* aptr1 = X + (size_t)ar1 * NF + aq * 8;
  const int awr0 = arl0 * PAD + aq * 8;
  const int awr1 = awr0 + 64 * PAD;
  const int bcl = tid >> 1, bh = tid & 1;
  const unsigned short* bptr = Wt + (size_t)(n0 + bcl) * NF + bh * 16;
  const int bwr = bcl * PAD + bh * 16;

  f32x4 acc[4][4];
#pragma unroll
  for (int m = 0; m < 4; m++)
#pragma unroll
    for (int n = 0; n < 4; n++) acc[m][n] = (f32x4)0.0f;

  float4 ra[3][4]; short8 rb0[3], rb1[3];   // depth-3 prefetch ring

#define LOADR(ks, j) do { \
    ra[j][0] = *reinterpret_cast<const float4*>(aptr0 + (ks) * 32); \
    ra[j][1] = *reinterpret_cast<const float4*>(aptr0 + (ks) * 32 + 4); \
    ra[j][2] = *reinterpret_cast<const float4*>(aptr1 + (ks) * 32); \
    ra[j][3] = *reinterpret_cast<const float4*>(aptr1 + (ks) * 32 + 4); \
    rb0[j] = *reinterpret_cast<const short8*>(bptr + (ks) * 32); \
    rb1[j] = *reinterpret_cast<const short8*>(bptr + (ks) * 32 + 8); \
  } while (0)

#define STAGE(b, j) do { \
    *reinterpret_cast<short8*>(&Asm[b][awr0]) = cvt8(ra[j][0], ra[j][1]); \
    *reinterpret_cast<short8*>(&Asm[b][awr1]) = cvt8(ra[j][2], ra[j][3]); \
    *reinterpret_cast<short8*>(&Bsm[b][bwr]) = rb0[j]; \
    *reinterpret_cast<short8*>(&Bsm[b][bwr + 8]) = rb1[j]; \
  } while (0)

#define COMPUTE(b) do { \
    short8 af[4], bfr[4]; \
    _Pragma("unroll") \
    for (int mi = 0; mi < 4; mi++) \
      af[mi] = *reinterpret_cast<const short8*>(&Asm[b][(wm * 64 + mi * 16 + l15) * PAD + kq * 8]); \
    _Pragma("unroll") \
    for (int ni = 0; ni < 4; ni++) \
      bfr[ni] = *reinterpret_cast<const short8*>(&Bsm[b][(wn * 64 + ni * 16 + l15) * PAD + kq * 8]); \
    _Pragma("unroll") \
    for (int mi = 0; mi < 4; mi++) \
      _Pragma("unroll") \
      for (int ni = 0; ni < 4; ni++) \
        acc[mi][ni] = __builtin_amdgcn_mfma_f32_16x16x32_bf16(af[mi], bfr[ni], acc[mi][ni], 0, 0, 0); \
  } while (0)

  LOADR(0, 0);
  LOADR(1, 1);
  LOADR(2, 2);
  STAGE(0, 0);
  block_sync_lds();

#pragma unroll
  for (int p = 0; p < 16; p++) {
    if (p + 3 < 16) LOADR(p + 3, (p + 3) % 3);
    COMPUTE(p & 1);
    if (p + 1 < 16) STAGE((p + 1) & 1, (p + 1) % 3);
    block_sync_lds();
  }
#undef LOADR
#undef STAGE
#undef COMPUTE

  // epilogue: bias + relu, store bf16.  C/D layout: col=lane&15, row=(lane>>4)*4+i
#pragma unroll
  for (int ni = 0; ni < 4; ni++) {
    int col = n0 + wn * 64 + ni * 16 + l15;
    float bsv = bias[col];
#pragma unroll
    for (int mi = 0; mi < 4; mi++) {
      int rb2 = m0 + wm * 64 + mi * 16 + kq * 4;
#pragma unroll
      for (int i = 0; i < 4; i++) {
        int r = rb2 + i;
        if (r < NN) {
          float v = acc[mi][ni][i] + bsv;
          H[(size_t)r * NH + col] = f2bf(v > 0.f ? v : 0.f);
        }
      }
    }
  }
}

// ---- GEMM2 (MFMA): h2 = relu(H @ We + be); x0b = bf16(h2); out = t0*h2 -----
__global__ __launch_bounds__(256) void gemm2_kernel(
    const unsigned short* __restrict__ H, const unsigned short* __restrict__ Web,
    const float* __restrict__ be, const float* __restrict__ temp,
    unsigned short* __restrict__ x0b, float* __restrict__ out) {
  const int tid = threadIdx.x;
  const int lane = tid & 63;
  const int wave = tid >> 6;
  const int l15 = lane & 15, kq = lane >> 4;
  const int rbase = blockIdx.x * 64 + wave * 16;
  int rr = rbase + l15; if (rr >= NN) rr = NN - 1;
  const unsigned short* hrow = H + (size_t)rr * NH + kq * 8;
  const unsigned short* wrow = Web + (size_t)l15 * 256 + kq * 8;

  f32x4 acc[2];
  acc[0] = (f32x4)0.0f; acc[1] = (f32x4)0.0f;
#pragma unroll
  for (int ks = 0; ks < 8; ks++) {
    short8 a = *reinterpret_cast<const short8*>(hrow + ks * 32);
    short8 b0 = *reinterpret_cast<const short8*>(wrow + ks * 32);
    short8 b1 = *reinterpret_cast<const short8*>(wrow + 16 * 256 + ks * 32);
    acc[0] = __builtin_amdgcn_mfma_f32_16x16x32_bf16(a, b0, acc[0], 0, 0, 0);
    acc[1] = __builtin_amdgcn_mfma_f32_16x16x32_bf16(a, b1, acc[1], 0, 0, 0);
  }
  const float t0 = temp[0];
#pragma unroll
  for (int nt = 0; nt < 2; nt++) {
    int col = nt * 16 + l15;
    float bv = be[col];
#pragma unroll
    for (int i = 0; i < 4; i++) {
      int row = rbase + kq * 4 + i;
      if (row < NN) {
        float v = acc[nt][i] + bv;
        v = v > 0.f ? v : 0.f;
        x0b[(size_t)row * NC + col] = f2bf(v);
        out[(size_t)row * NC + col] = t0 * v;
      }
    }
  }
}

// ---- graph normalization + CSR build ---------------------------------------
// dc[i]: bits[63:44] = count, bits[43:0] = fixed-point deg (scale 2^32)
__global__ void node_init_kernel(u64* dc) {
  int i = blockIdx.x * 256 + threadIdx.x;
  if (i < NN) dc[i] = (1ULL << 44) | (1ULL << 32);   // self-loop: cnt=1, deg=1.0
}

__global__ void edge_deg_kernel(const int* __restrict__ ei, const float* __restrict__ ew,
                                u64* dc) {
  int e = blockIdx.x * 256 + threadIdx.x;
  if (e < EE) {
    int col = ei[EE + e];
    u64 v = (1ULL << 44) | (u64)((double)ew[e] * 4294967296.0);
    atomicAdd(&dc[col], v);
  }
}

__global__ void dis_kernel(const u64* __restrict__ dc, float* __restrict__ dis,
                           int* __restrict__ cnt) {
  int i = blockIdx.x * 256 + threadIdx.x;
  if (i < NN) {
    u64 v = dc[i];
    cnt[i] = (int)(v >> 44);
    float deg = (float)((double)(v & 0xFFFFFFFFFFFULL) * (1.0 / 4294967296.0));
    dis[i] = rsqrtf(deg);
  }
}

// scans use PADDED counts (mult of 16) so every CSR list is a whole number of
// 16-batches in spmm (no serial remainder tails).
__global__ void scan1_kernel(const int* __restrict__ cnt, int* bsum) {
  __shared__ int ws[4];
  const int tid = threadIdx.x;
  int base = blockIdx.x * 1024 + tid * 4;
  int s = 0;
#pragma unroll
  for (int j = 0; j < 4; j++) { int i = base + j; if (i < NN) s += padc(cnt[i]); }
  for (int off = 32; off > 0; off >>= 1) s += __shfl_down(s, off);
  if ((tid & 63) == 0) ws[tid >> 6] = s;
  __syncthreads();
  if (tid == 0) bsum[blockIdx.x] = ws[0] + ws[1] + ws[2] + ws[3];
}

__global__ void scan2_kernel(const int* __restrict__ bsum, int* bofs, int* offs) {
  if (threadIdx.x == 0) {
    int run = 0;
    for (int i = 0; i < 98; i++) { bofs[i] = run; run += bsum[i]; }
    offs[NN] = run;
  }
}

__global__ void scan3_kernel(const int* __restrict__ cnt, const int* __restrict__ bofs,
                             int* offs, int* cursor) {
  __shared__ int wsum[4];
  const int tid = threadIdx.x;
  const int lane = tid & 63, wv = tid >> 6;
  int base = blockIdx.x * 1024 + tid * 4;
  int v[4]; int s = 0;
#pragma unroll
  for (int j = 0; j < 4; j++) { int i = base + j; v[j] = (i < NN) ? padc(cnt[i]) : 0; s += v[j]; }
  int incl = s;
  for (int off = 1; off < 64; off <<= 1) {
    int t = __shfl_up(incl, off);
    if (lane >= off) incl += t;
  }
  if (lane == 63) wsum[wv] = incl;
  __syncthreads();
  int woff = bofs[blockIdx.x];
  for (int w = 0; w < wv; w++) woff += wsum[w];
  int excl = woff + incl - s;
#pragma unroll
  for (int j = 0; j < 4; j++) {
    int i = base + j;
    if (i < NN) { offs[i] = excl; cursor[i] = excl; }
    excl += v[j];
  }
}

// pk[slot]: low 32 = row index, high 32 = fp32 weight bits
__global__ void fill_kernel(const int* __restrict__ ei, const float* __restrict__ ew,
                            const float* __restrict__ dis, int* cursor,
                            u64* __restrict__ pk) {
  int t = blockIdx.x * 256 + threadIdx.x;
  if (t < EE) {
    int r = ei[t], c = ei[EE + t];
    int slot = atomicAdd(&cursor[c], 1);
    unsigned int wb = __float_as_uint(dis[r] * ew[t] * dis[c]);
    pk[slot] = (u64)(unsigned int)r | ((u64)wb << 32);
  } else if (t < EE + NN) {
    int i = t - EE;
    int slot = atomicAdd(&cursor[i], 1);
    float d = dis[i];
    unsigned int wb = __float_as_uint(d * d);
    pk[slot] = (u64)(unsigned int)i | ((u64)wb << 32);
  }
}

// zero-fill the padding gap [cursor[i], offs[i+1]) with row=0, weight=0
__global__ void pad_kernel(const int* __restrict__ cursor, const int* __restrict__ offs,
                           u64* __restrict__ pk) {
  int i = blockIdx.x * 256 + threadIdx.x;
  if (i < NN) {
    int j = cursor[i], e = offs[i + 1];
    for (; j < e; j++) pk[j] = 0;
  }
}

// ---- SpMM (bf16 xk): xout = A*xin.  Lists padded to mult-16 -> pure 16-batch
// loop (16 pk loads -> 16 independent gathers -> FMA), no serial remainders.
__global__ __launch_bounds__(256) void spmm_kernel(
    const int* __restrict__ offs, const u64* __restrict__ pk,
    const unsigned short* __restrict__ xin, unsigned short* __restrict__ xout) {
  const int tid = threadIdx.x;
  const int node = blockIdx.x * 8 + (tid >> 5);
  const int f = tid & 31;
  const int s = offs[node], e = offs[node + 1];
  float aa[4] = {0.f, 0.f, 0.f, 0.f};
  for (int j = s; j < e; j += 16) {
    u64 p[16];
#pragma unroll
    for (int i = 0; i < 16; i++) p[i] = pk[j + i];
    float x[16];
#pragma unroll
    for (int i = 0; i < 16; i++)
      x[i] = bf2f(xin[(size_t)(unsigned int)p[i] * NC + f]);
#pragma unroll
    for (int i = 0; i < 16; i++)
      aa[i & 3] += __uint_as_float((unsigned int)(p[i] >> 32)) * x[i];
  }
  xout[(size_t)node * NC + f] = f2bf((aa[0] + aa[1]) + (aa[2] + aa[3]));
}

// ---- final weighted sum: out += sum_k temp[k+1] * xk_k ---------------------
__global__ __launch_bounds__(256) void wsum_kernel(
    const unsigned short* __restrict__ S07,   // slices 0..7 (H region)
    const unsigned short* __restrict__ S8, const unsigned short* __restrict__ S9,
    float* __restrict__ out, const float* __restrict__ temp) {
  int idx = blockIdx.x * 256 + threadIdx.x;   // 12500*256 = 3.2M exact
  float s = out[idx];
#pragma unroll
  for (int k = 0; k < 8; k++)
    s += temp[k + 1] * bf2f(S07[(size_t)k * NN * NC + idx]);
  s += temp[9] * bf2f(S8[idx]);
  s += temp[10] * bf2f(S9[idx]);
  out[idx] = s;
}

extern "C" void kernel_launch(void* const* d_in, const int* in_sizes, int n_in,
                              void* d_out, int out_size, void* d_ws, size_t ws_size,
                              hipStream_t stream) {
  const float* X    = (const float*)d_in[0];
  const float* EA   = (const float*)d_in[1];
  const float* Ws   = (const float*)d_in[2];
  const float* bs   = (const float*)d_in[3];
  const float* We   = (const float*)d_in[4];
  const float* be   = (const float*)d_in[5];
  const float* temp = (const float*)d_in[6];
  const int*   ei   = (const int*)d_in[7];
  float* out = (float*)d_out;

  size_t off = 0;
  auto alloc = [&](size_t n) { void* p = (char*)d_ws + off; off += (n + 255) & ~(size_t)255; return p; };
  unsigned short* Wt  = (unsigned short*)alloc((size_t)NF * NH * 2);   // 256 KB
  unsigned short* Web = (unsigned short*)alloc((size_t)NH * NC * 2);   // 16 KB
  unsigned short* H   = (unsigned short*)alloc((size_t)NN * NH * 2);   // 51.2 MB = slices 0..7
  unsigned short* x0b = (unsigned short*)alloc((size_t)NN * NC * 2);   // 6.4 MB (gemm2 out)
  unsigned short* xk8 = (unsigned short*)alloc((size_t)NN * NC * 2);   // slice 8
  unsigned short* xk9 = (unsigned short*)alloc((size_t)NN * NC * 2);   // slice 9
  u64*   dc   = (u64*)alloc((size_t)NN * 8);                           // 800 KB
  float* dis  = (float*)alloc((size_t)NN * 4);
  int*   cnt  = (int*)alloc((size_t)NN * 4);
  int*   offs = (int*)alloc((size_t)(NN + 1) * 4);
  int*   cursor = (int*)alloc((size_t)NN * 4);
  int*   bsum = (int*)alloc(98 * 4);
  int*   bofs = (int*)alloc(98 * 4);
  u64*   pk   = (u64*)alloc((size_t)(EE + 16 * NN) * 8);               // 25.6 MB (padded)

  // MLP front-end
  convwb_kernel<<<544, 256, 0, stream>>>(Ws, We, Wt, Web);
  gemm1_kernel<<<1564, 256, 0, stream>>>(X, Wt, bs, H);
  gemm2_kernel<<<1563, 256, 0, stream>>>(H, Web, be, temp, x0b, out);

  // gcn_norm + padded CSR build (by col, so SpMM is atomic-free)
  node_init_kernel<<<391, 256, 0, stream>>>(dc);
  edge_deg_kernel<<<6250, 256, 0, stream>>>(ei, EA, dc);
  dis_kernel<<<391, 256, 0, stream>>>(dc, dis, cnt);
  scan1_kernel<<<98, 256, 0, stream>>>(cnt, bsum);
  scan2_kernel<<<1, 64, 0, stream>>>(bsum, bofs, offs);
  scan3_kernel<<<98, 256, 0, stream>>>(cnt, bofs, offs, cursor);
  fill_kernel<<<6641, 256, 0, stream>>>(ei, EA, dis, cursor, pk);
  pad_kernel<<<391, 256, 0, stream>>>(cursor, offs, pk);

  // K=10 propagation; slice k lives in H (k<8) else xk8/xk9.  NOTE: H is dead
  // after gemm2, so its 51.2 MB is reused as 8 xk slices.
  auto slice = [&](int k) -> unsigned short* {
    return (k < 8) ? H + (size_t)k * NN * NC : (k == 8 ? xk8 : xk9);
  };
  const unsigned short* xin = x0b;
  for (int k = 0; k < KP; k++) {
    spmm_kernel<<<12500, 256, 0, stream>>>(offs, pk, xin, slice(k));
    xin = slice(k);
  }
  wsum_kernel<<<12500, 256, 0, stream>>>(H, xk8, xk9, out, temp);
}

// Round 9
// 561.025 us; speedup vs baseline: 6.0076x; 1.2288x over previous
//
#include <hip/hip_runtime.h>

typedef __attribute__((ext_vector_type(8))) short short8;
typedef __attribute__((ext_vector_type(4))) float f32x4;
typedef unsigned long long u64;

constexpr int NN = 100000;
constexpr int EE = 1600000;
constexpr int NF = 512;
constexpr int NH = 256;
constexpr int NC = 32;
constexpr int KP = 10;

__device__ __forceinline__ unsigned short f2bf(float f) {
  unsigned int u = __float_as_uint(f);
  u += 0x7FFFu + ((u >> 16) & 1u);   // round-to-nearest-even
  return (unsigned short)(u >> 16);
}
__device__ __forceinline__ float bf2f(unsigned short s) {
  return __uint_as_float(((unsigned int)s) << 16);
}
__device__ __forceinline__ int padc(int c) { return (c + 15) & ~15; }

__device__ __forceinline__ short8 cvt8(float4 a0, float4 a1) {
  union { unsigned int u[4]; short8 s; } r;
  asm("v_cvt_pk_bf16_f32 %0, %1, %2" : "=v"(r.u[0]) : "v"(a0.x), "v"(a0.y));
  asm("v_cvt_pk_bf16_f32 %0, %1, %2" : "=v"(r.u[1]) : "v"(a0.z), "v"(a0.w));
  asm("v_cvt_pk_bf16_f32 %0, %1, %2" : "=v"(r.u[2]) : "v"(a1.x), "v"(a1.y));
  asm("v_cvt_pk_bf16_f32 %0, %1, %2" : "=v"(r.u[3]) : "v"(a1.z), "v"(a1.w));
  return r.s;
}

// Barrier with LDS-only drain: keeps global loads (into registers) in flight
// across the barrier — avoids the compiler's vmcnt(0) drain of __syncthreads.
__device__ __forceinline__ void block_sync_lds() {
  asm volatile("s_waitcnt lgkmcnt(0)" ::: "memory");
  __builtin_amdgcn_s_barrier();
}

// ---- weight conversion: Wt[col][k]=bf(Ws[k][col]); Web[col][k]=bf(We[k][col])
__global__ void convwb_kernel(const float* __restrict__ Ws, const float* __restrict__ We,
                              unsigned short* __restrict__ Wt, unsigned short* __restrict__ Web) {
  int idx = blockIdx.x * 256 + threadIdx.x;      // 544*256 = 139264
  if (idx < 131072) {
    int col = idx >> 9, k = idx & 511;
    Wt[idx] = f2bf(Ws[(size_t)k * NH + col]);
  } else {
    int j = idx - 131072;
    int col = j >> 8, k = j & 255;
    Web[j] = f2bf(We[(size_t)k * NC + col]);
  }
}

// ---- GEMM1: H = relu(X[100000,512] @ W[512,256] + b), bf16 MFMA ------------
// R3 structure (best measured: 134 us). Do not touch: R1/R2/R4 redesigns all
// regressed; R7 confirmed this is the stable local optimum.
__global__ __launch_bounds__(256, 3) void gemm1_kernel(
    const float* __restrict__ X, const unsigned short* __restrict__ Wt,
    const float* __restrict__ bias, unsigned short* __restrict__ H) {
  constexpr int PAD = 36;
  __shared__ __align__(16) unsigned short Asm[2][128 * PAD];
  __shared__ __align__(16) unsigned short Bsm[2][128 * PAD];
  const int tid = threadIdx.x;
  const int lane = tid & 63;
  const int wave = tid >> 6;
  const int wm = wave >> 1, wn = wave & 1;
  const int l15 = lane & 15, kq = lane >> 4;
  const int m0 = (blockIdx.x >> 1) * 128;
  const int n0 = (blockIdx.x & 1) * 128;

  const int arl0 = tid >> 2, aq = tid & 3;
  int ar0 = m0 + arl0; if (ar0 >= NN) ar0 = NN - 1;
  int ar1 = m0 + arl0 + 64; if (ar1 >= NN) ar1 = NN - 1;
  const float* aptr0 = X + (size_t)ar0 * NF + aq * 8;
  const float* aptr1 = X + (size_t)ar1 * NF + aq * 8;
  const int awr0 = arl0 * PAD + aq * 8;
  const int awr1 = awr0 + 64 * PAD;
  const int bcl = tid >> 1, bh = tid & 1;
  const unsigned short* bptr = Wt + (size_t)(n0 + bcl) * NF + bh * 16;
  const int bwr = bcl * PAD + bh * 16;

  f32x4 acc[4][4];
#pragma unroll
  for (int m = 0; m < 4; m++)
#pragma unroll
    for (int n = 0; n < 4; n++) acc[m][n] = (f32x4)0.0f;

  float4 ra[3][4]; short8 rb0[3], rb1[3];   // depth-3 prefetch ring

#define LOADR(ks, j) do { \
    ra[j][0] = *reinterpret_cast<const float4*>(aptr0 + (ks) * 32); \
    ra[j][1] = *reinterpret_cast<const float4*>(aptr0 + (ks) * 32 + 4); \
    ra[j][2] = *reinterpret_cast<const float4*>(aptr1 + (ks) * 32); \
    ra[j][3] = *reinterpret_cast<const float4*>(aptr1 + (ks) * 32 + 4); \
    rb0[j] = *reinterpret_cast<const short8*>(bptr + (ks) * 32); \
    rb1[j] = *reinterpret_cast<const short8*>(bptr + (ks) * 32 + 8); \
  } while (0)

#define STAGE(b, j) do { \
    *reinterpret_cast<short8*>(&Asm[b][awr0]) = cvt8(ra[j][0], ra[j][1]); \
    *reinterpret_cast<short8*>(&Asm[b][awr1]) = cvt8(ra[j][2], ra[j][3]); \
    *reinterpret_cast<short8*>(&Bsm[b][bwr]) = rb0[j]; \
    *reinterpret_cast<short8*>(&Bsm[b][bwr + 8]) = rb1[j]; \
  } while (0)

#define COMPUTE(b) do { \
    short8 af[4], bfr[4]; \
    _Pragma("unroll") \
    for (int mi = 0; mi < 4; mi++) \
      af[mi] = *reinterpret_cast<const short8*>(&Asm[b][(wm * 64 + mi * 16 + l15) * PAD + kq * 8]); \
    _Pragma("unroll") \
    for (int ni = 0; ni < 4; ni++) \
      bfr[ni] = *reinterpret_cast<const short8*>(&Bsm[b][(wn * 64 + ni * 16 + l15) * PAD + kq * 8]); \
    _Pragma("unroll") \
    for (int mi = 0; mi < 4; mi++) \
      _Pragma("unroll") \
      for (int ni = 0; ni < 4; ni++) \
        acc[mi][ni] = __builtin_amdgcn_mfma_f32_16x16x32_bf16(af[mi], bfr[ni], acc[mi][ni], 0, 0, 0); \
  } while (0)

  LOADR(0, 0);
  LOADR(1, 1);
  LOADR(2, 2);
  STAGE(0, 0);
  block_sync_lds();

#pragma unroll
  for (int p = 0; p < 16; p++) {
    if (p + 3 < 16) LOADR(p + 3, (p + 3) % 3);
    COMPUTE(p & 1);
    if (p + 1 < 16) STAGE((p + 1) & 1, (p + 1) % 3);
    block_sync_lds();
  }
#undef LOADR
#undef STAGE
#undef COMPUTE

  // epilogue: bias + relu, store bf16.  C/D layout: col=lane&15, row=(lane>>4)*4+i
#pragma unroll
  for (int ni = 0; ni < 4; ni++) {
    int col = n0 + wn * 64 + ni * 16 + l15;
    float bsv = bias[col];
#pragma unroll
    for (int mi = 0; mi < 4; mi++) {
      int rb2 = m0 + wm * 64 + mi * 16 + kq * 4;
#pragma unroll
      for (int i = 0; i < 4; i++) {
        int r = rb2 + i;
        if (r < NN) {
          float v = acc[mi][ni][i] + bsv;
          H[(size_t)r * NH + col] = f2bf(v > 0.f ? v : 0.f);
        }
      }
    }
  }
}

// ---- GEMM2 (MFMA): h2 = relu(H @ We + be); x0b = bf16(h2); out = t0*h2 -----
__global__ __launch_bounds__(256) void gemm2_kernel(
    const unsigned short* __restrict__ H, const unsigned short* __restrict__ Web,
    const float* __restrict__ be, const float* __restrict__ temp,
    unsigned short* __restrict__ x0b, float* __restrict__ out) {
  const int tid = threadIdx.x;
  const int lane = tid & 63;
  const int wave = tid >> 6;
  const int l15 = lane & 15, kq = lane >> 4;
  const int rbase = blockIdx.x * 64 + wave * 16;
  int rr = rbase + l15; if (rr >= NN) rr = NN - 1;
  const unsigned short* hrow = H + (size_t)rr * NH + kq * 8;
  const unsigned short* wrow = Web + (size_t)l15 * 256 + kq * 8;

  f32x4 acc[2];
  acc[0] = (f32x4)0.0f; acc[1] = (f32x4)0.0f;
#pragma unroll
  for (int ks = 0; ks < 8; ks++) {
    short8 a = *reinterpret_cast<const short8*>(hrow + ks * 32);
    short8 b0 = *reinterpret_cast<const short8*>(wrow + ks * 32);
    short8 b1 = *reinterpret_cast<const short8*>(wrow + 16 * 256 + ks * 32);
    acc[0] = __builtin_amdgcn_mfma_f32_16x16x32_bf16(a, b0, acc[0], 0, 0, 0);
    acc[1] = __builtin_amdgcn_mfma_f32_16x16x32_bf16(a, b1, acc[1], 0, 0, 0);
  }
  const float t0 = temp[0];
#pragma unroll
  for (int nt = 0; nt < 2; nt++) {
    int col = nt * 16 + l15;
    float bv = be[col];
#pragma unroll
    for (int i = 0; i < 4; i++) {
      int row = rbase + kq * 4 + i;
      if (row < NN) {
        float v = acc[nt][i] + bv;
        v = v > 0.f ? v : 0.f;
        x0b[(size_t)row * NC + col] = f2bf(v);
        out[(size_t)row * NC + col] = t0 * v;
      }
    }
  }
}

// ---- graph normalization + CSR build ---------------------------------------
// dc[i]: bits[63:44] = count, bits[43:0] = fixed-point deg (scale 2^32)
__global__ void node_init_kernel(u64* dc) {
  int i = blockIdx.x * 256 + threadIdx.x;
  if (i < NN) dc[i] = (1ULL << 44) | (1ULL << 32);   // self-loop: cnt=1, deg=1.0
}

__global__ void edge_deg_kernel(const int* __restrict__ ei, const float* __restrict__ ew,
                                u64* dc) {
  int e = blockIdx.x * 256 + threadIdx.x;
  if (e < EE) {
    int col = ei[EE + e];
    u64 v = (1ULL << 44) | (u64)((double)ew[e] * 4294967296.0);
    atomicAdd(&dc[col], v);
  }
}

__global__ void dis_kernel(const u64* __restrict__ dc, float* __restrict__ dis,
                           int* __restrict__ cnt) {
  int i = blockIdx.x * 256 + threadIdx.x;
  if (i < NN) {
    u64 v = dc[i];
    cnt[i] = (int)(v >> 44);
    float deg = (float)((double)(v & 0xFFFFFFFFFFFULL) * (1.0 / 4294967296.0));
    dis[i] = rsqrtf(deg);
  }
}

// scans use PADDED counts (mult of 16) so every CSR list is a whole number of
// 8/16-batches in spmm (no serial remainder tails).
__global__ void scan1_kernel(const int* __restrict__ cnt, int* bsum) {
  __shared__ int ws[4];
  const int tid = threadIdx.x;
  int base = blockIdx.x * 1024 + tid * 4;
  int s = 0;
#pragma unroll
  for (int j = 0; j < 4; j++) { int i = base + j; if (i < NN) s += padc(cnt[i]); }
  for (int off = 32; off > 0; off >>= 1) s += __shfl_down(s, off);
  if ((tid & 63) == 0) ws[tid >> 6] = s;
  __syncthreads();
  if (tid == 0) bsum[blockIdx.x] = ws[0] + ws[1] + ws[2] + ws[3];
}

__global__ void scan2_kernel(const int* __restrict__ bsum, int* bofs, int* offs) {
  if (threadIdx.x == 0) {
    int run = 0;
    for (int i = 0; i < 98; i++) { bofs[i] = run; run += bsum[i]; }
    offs[NN] = run;
  }
}

__global__ void scan3_kernel(const int* __restrict__ cnt, const int* __restrict__ bofs,
                             int* offs, int* cursor) {
  __shared__ int wsum[4];
  const int tid = threadIdx.x;
  const int lane = tid & 63, wv = tid >> 6;
  int base = blockIdx.x * 1024 + tid * 4;
  int v[4]; int s = 0;
#pragma unroll
  for (int j = 0; j < 4; j++) { int i = base + j; v[j] = (i < NN) ? padc(cnt[i]) : 0; s += v[j]; }
  int incl = s;
  for (int off = 1; off < 64; off <<= 1) {
    int t = __shfl_up(incl, off);
    if (lane >= off) incl += t;
  }
  if (lane == 63) wsum[wv] = incl;
  __syncthreads();
  int woff = bofs[blockIdx.x];
  for (int w = 0; w < wv; w++) woff += wsum[w];
  int excl = woff + incl - s;
#pragma unroll
  for (int j = 0; j < 4; j++) {
    int i = base + j;
    if (i < NN) { offs[i] = excl; cursor[i] = excl; }
    excl += v[j];
  }
}

// pk[slot]: low 32 = row index, high 32 = fp32 weight bits
__global__ void fill_kernel(const int* __restrict__ ei, const float* __restrict__ ew,
                            const float* __restrict__ dis, int* cursor,
                            u64* __restrict__ pk) {
  int t = blockIdx.x * 256 + threadIdx.x;
  if (t < EE) {
    int r = ei[t], c = ei[EE + t];
    int slot = atomicAdd(&cursor[c], 1);
    unsigned int wb = __float_as_uint(dis[r] * ew[t] * dis[c]);
    pk[slot] = (u64)(unsigned int)r | ((u64)wb << 32);
  } else if (t < EE + NN) {
    int i = t - EE;
    int slot = atomicAdd(&cursor[i], 1);
    float d = dis[i];
    unsigned int wb = __float_as_uint(d * d);
    pk[slot] = (u64)(unsigned int)i | ((u64)wb << 32);
  }
}

// zero-fill the padding gap [cursor[i], offs[i+1]) with row=0, weight=0
__global__ void pad_kernel(const int* __restrict__ cursor, const int* __restrict__ offs,
                           u64* __restrict__ pk) {
  int i = blockIdx.x * 256 + threadIdx.x;
  if (i < NN) {
    int j = cursor[i], e = offs[i + 1];
    for (; j < e; j++) pk[j] = 0;
  }
}

// ---- SpMM (bf16 xk): xout = A*xin ------------------------------------------
// VMEM-issue optimized: 8 lanes per node, each lane owns 4 features and
// gathers 8 BYTES per edge (u64 = 4 bf16) instead of 2 -> one wave carries
// 8 nodes -> 4x fewer VMEM instructions for identical line traffic.
// Lists padded to mult-16 (built above) -> pure 8-batches, no remainders.
__global__ __launch_bounds__(256) void spmm_kernel(
    const int* __restrict__ offs, const u64* __restrict__ pk,
    const unsigned short* __restrict__ xin, unsigned short* __restrict__ xout) {
  const int tid = threadIdx.x;
  const int node = blockIdx.x * 32 + (tid >> 3);   // 3125*32 = 100000 exact
  const int fq = (tid & 7) * 4;                    // feature quad base
  const int s = offs[node], e = offs[node + 1];
  float a0 = 0.f, a1 = 0.f, a2 = 0.f, a3 = 0.f;
  for (int j = s; j < e; j += 8) {
    u64 p[8];
#pragma unroll
    for (int i = 0; i < 8; i++) p[i] = pk[j + i];
    u64 q[8];
#pragma unroll
    for (int i = 0; i < 8; i++)
      q[i] = *reinterpret_cast<const u64*>(xin + (size_t)(unsigned int)p[i] * NC + fq);
#pragma unroll
    for (int i = 0; i < 8; i++) {
      const float w = __uint_as_float((unsigned int)(p[i] >> 32));
      a0 += w * bf2f((unsigned short)(q[i]));
      a1 += w * bf2f((unsigned short)(q[i] >> 16));
      a2 += w * bf2f((unsigned short)(q[i] >> 32));
      a3 += w * bf2f((unsigned short)(q[i] >> 48));
    }
  }
  // pack 4 bf16 (RNE via cvt_pk) and store 8B; 8 lanes = 64B contiguous
  unsigned int lo, hi;
  asm("v_cvt_pk_bf16_f32 %0, %1, %2" : "=v"(lo) : "v"(a0), "v"(a1));
  asm("v_cvt_pk_bf16_f32 %0, %1, %2" : "=v"(hi) : "v"(a2), "v"(a3));
  *reinterpret_cast<u64*>(xout + (size_t)node * NC + fq) =
      (u64)lo | ((u64)hi << 32);
}

// ---- final weighted sum: out += sum_k temp[k+1] * xk_k ---------------------
__global__ __launch_bounds__(256) void wsum_kernel(
    const unsigned short* __restrict__ S07,   // slices 0..7 (H region)
    const unsigned short* __restrict__ S8, const unsigned short* __restrict__ S9,
    float* __restrict__ out, const float* __restrict__ temp) {
  int idx = blockIdx.x * 256 + threadIdx.x;   // 12500*256 = 3.2M exact
  float s = out[idx];
#pragma unroll
  for (int k = 0; k < 8; k++)
    s += temp[k + 1] * bf2f(S07[(size_t)k * NN * NC + idx]);
  s += temp[9] * bf2f(S8[idx]);
  s += temp[10] * bf2f(S9[idx]);
  out[idx] = s;
}

extern "C" void kernel_launch(void* const* d_in, const int* in_sizes, int n_in,
                              void* d_out, int out_size, void* d_ws, size_t ws_size,
                              hipStream_t stream) {
  const float* X    = (const float*)d_in[0];
  const float* EA   = (const float*)d_in[1];
  const float* Ws   = (const float*)d_in[2];
  const float* bs   = (const float*)d_in[3];
  const float* We   = (const float*)d_in[4];
  const float* be   = (const float*)d_in[5];
  const float* temp = (const float*)d_in[6];
  const int*   ei   = (const int*)d_in[7];
  float* out = (float*)d_out;

  size_t off = 0;
  auto alloc = [&](size_t n) { void* p = (char*)d_ws + off; off += (n + 255) & ~(size_t)255; return p; };
  unsigned short* Wt  = (unsigned short*)alloc((size_t)NF * NH * 2);   // 256 KB
  unsigned short* Web = (unsigned short*)alloc((size_t)NH * NC * 2);   // 16 KB
  unsigned short* H   = (unsigned short*)alloc((size_t)NN * NH * 2);   // 51.2 MB = slices 0..7
  unsigned short* x0b = (unsigned short*)alloc((size_t)NN * NC * 2);   // 6.4 MB (gemm2 out)
  unsigned short* xk8 = (unsigned short*)alloc((size_t)NN * NC * 2);   // slice 8
  unsigned short* xk9 = (unsigned short*)alloc((size_t)NN * NC * 2);   // slice 9
  u64*   dc   = (u64*)alloc((size_t)NN * 8);                           // 800 KB
  float* dis  = (float*)alloc((size_t)NN * 4);
  int*   cnt  = (int*)alloc((size_t)NN * 4);
  int*   offs = (int*)alloc((size_t)(NN + 1) * 4);
  int*   cursor = (int*)alloc((size_t)NN * 4);
  int*   bsum = (int*)alloc(98 * 4);
  int*   bofs = (int*)alloc(98 * 4);
  u64*   pk   = (u64*)alloc((size_t)(EE + 16 * NN) * 8);               // 25.6 MB (padded)

  // MLP front-end
  convwb_kernel<<<544, 256, 0, stream>>>(Ws, We, Wt, Web);
  gemm1_kernel<<<1564, 256, 0, stream>>>(X, Wt, bs, H);
  gemm2_kernel<<<1563, 256, 0, stream>>>(H, Web, be, temp, x0b, out);

  // gcn_norm + padded CSR build (by col, so SpMM is atomic-free)
  node_init_kernel<<<391, 256, 0, stream>>>(dc);
  edge_deg_kernel<<<6250, 256, 0, stream>>>(ei, EA, dc);
  dis_kernel<<<391, 256, 0, stream>>>(dc, dis, cnt);
  scan1_kernel<<<98, 256, 0, stream>>>(cnt, bsum);
  scan2_kernel<<<1, 64, 0, stream>>>(bsum, bofs, offs);
  scan3_kernel<<<98, 256, 0, stream>>>(cnt, bofs, offs, cursor);
  fill_kernel<<<6641, 256, 0, stream>>>(ei, EA, dis, cursor, pk);
  pad_kernel<<<391, 256, 0, stream>>>(cursor, offs, pk);

  // K=10 propagation; slice k lives in H (k<8) else xk8/xk9.  NOTE: H is dead
  // after gemm2, so its 51.2 MB is reused as 8 xk slices.
  auto slice = [&](int k) -> unsigned short* {
    return (k < 8) ? H + (size_t)k * NN * NC : (k == 8 ? xk8 : xk9);
  };
  const unsigned short* xin = x0b;
  for (int k = 0; k < KP; k++) {
    spmm_kernel<<<3125, 256, 0, stream>>>(offs, pk, xin, slice(k));
    xin = slice(k);
  }
  wsum_kernel<<<12500, 256, 0, stream>>>(H, xk8, xk9, out, temp);
}